// Round 1
// baseline (5369.006 us; speedup 1.0000x reference)
//
#include <hip/hip_runtime.h>

#define BB 8
#define CC 64
#define NPT 32768
#define RR 32
#define R3 32768
#define BN_EPS 1e-4f

// ---------------- reduction helper ----------------
__device__ __forceinline__ float blockReduceSum256(float v, float* sbuf) {
    int tid = threadIdx.x;
    sbuf[tid] = v; __syncthreads();
    for (int off = 128; off > 0; off >>= 1) {
        if (tid < off) sbuf[tid] += sbuf[tid + off];
        __syncthreads();
    }
    float r = sbuf[0]; __syncthreads();
    return r;
}

// ---------------- coord normalization ----------------
__global__ void k_mean(const float* __restrict__ coords, float* __restrict__ mean) {
    __shared__ float sbuf[256];
    int bd = blockIdx.x;             // b*3 + d
    const float* c = coords + (size_t)bd * NPT;
    float s = 0.f;
    for (int i = threadIdx.x; i < NPT; i += 256) s += c[i];
    float tot = blockReduceSum256(s, sbuf);
    if (threadIdx.x == 0) mean[bd] = tot / (float)NPT;
}

__global__ void k_maxmag(const float* __restrict__ coords, const float* __restrict__ mean,
                         float* __restrict__ maxmag) {
    __shared__ float sbuf[256];
    int b = blockIdx.x;
    float m0 = mean[b*3], m1 = mean[b*3+1], m2 = mean[b*3+2];
    const float* c = coords + (size_t)b * 3 * NPT;
    float mx = 0.f;
    for (int i = threadIdx.x; i < NPT; i += 256) {
        float x = c[i] - m0, y = c[NPT + i] - m1, z = c[2*NPT + i] - m2;
        mx = fmaxf(mx, x*x + y*y + z*z);
    }
    sbuf[threadIdx.x] = mx; __syncthreads();
    for (int off = 128; off > 0; off >>= 1) {
        if (threadIdx.x < off) sbuf[threadIdx.x] = fmaxf(sbuf[threadIdx.x], sbuf[threadIdx.x + off]);
        __syncthreads();
    }
    if (threadIdx.x == 0) maxmag[b] = sqrtf(sbuf[0]);
}

__global__ void k_norm(const float* __restrict__ coords, const float* __restrict__ mean,
                       const float* __restrict__ maxmag,
                       float* __restrict__ norm, int* __restrict__ idx, float* __restrict__ cnt) {
    int b = blockIdx.y;
    int n = blockIdx.x * 256 + threadIdx.x;
    float denom = maxmag[b] * 2.0f;
    int vi[3];
    #pragma unroll
    for (int d = 0; d < 3; d++) {
        float v = (coords[((size_t)b*3 + d)*NPT + n] - mean[b*3 + d]) / denom + 0.5f;
        v *= (float)RR;
        v = fminf(fmaxf(v, 0.0f), (float)(RR - 1));
        norm[((size_t)b*3 + d)*NPT + n] = v;
        vi[d] = (int)rintf(v);   // round half-to-even, matches jnp.round
    }
    int fl = (vi[0]*RR + vi[1])*RR + vi[2];
    idx[b*NPT + n] = fl;
    atomicAdd(&cnt[b*R3 + fl], 1.0f);
}

// ---------------- voxelize ----------------
__global__ void k_scatter(const float* __restrict__ feat, const int* __restrict__ idx,
                          float* __restrict__ grid) {
    int b = blockIdx.z, ci = blockIdx.y;
    int n = blockIdx.x * 256 + threadIdx.x;
    atomicAdd(&grid[((size_t)(b*CC + ci))*R3 + idx[b*NPT + n]],
              feat[((size_t)(b*CC + ci))*NPT + n]);
}

__global__ void k_divcnt(float* __restrict__ grid, const float* __restrict__ cnt) {
    size_t tot = (size_t)BB * CC * R3;
    for (size_t i = (size_t)blockIdx.x*256 + threadIdx.x; i < tot; i += (size_t)gridDim.x*256) {
        int b = (int)(i >> 21);          // / (C*R3) = 2^21
        int v = (int)(i & (R3 - 1));     // % R3
        grid[i] /= fmaxf(cnt[b*R3 + v], 1.0f);
    }
}

// ---------------- 3x3x3 conv + bias + BN-stats ----------------
__global__ __launch_bounds__(256) void k_conv(const float* __restrict__ in, float* __restrict__ out,
                                              const float* __restrict__ w, const float* __restrict__ bias,
                                              float* __restrict__ ssum, float* __restrict__ ssq) {
    __shared__ float tile[3 * 34 * 34];
    int d0 = blockIdx.x, cog = blockIdx.y, b = blockIdx.z;
    int tid = threadIdx.x;
    int co0 = cog * 8;
    float acc[4][8];
    #pragma unroll
    for (int q = 0; q < 4; q++)
        #pragma unroll
        for (int j = 0; j < 8; j++) acc[q][j] = bias[co0 + j];

    for (int ci = 0; ci < CC; ci++) {
        __syncthreads();
        for (int i = tid; i < 3*34*34; i += 256) {
            int dz = i / 1156, rem = i - dz*1156;
            int r = rem / 34, cc2 = rem - r*34;
            int g0 = d0 + dz - 1, g1 = r - 1, g2 = cc2 - 1;
            float v = 0.f;
            if (g0 >= 0 && g0 < RR && g1 >= 0 && g1 < RR && g2 >= 0 && g2 < RR)
                v = in[((size_t)(b*CC + ci))*R3 + (g0*RR + g1)*RR + g2];
            tile[i] = v;
        }
        __syncthreads();
        #pragma unroll
        for (int q = 0; q < 4; q++) {
            int p = tid + q*256;
            int d1 = p >> 5, d2 = p & 31;
            float r27[27];
            #pragma unroll
            for (int k0 = 0; k0 < 3; k0++)
                #pragma unroll
                for (int k1 = 0; k1 < 3; k1++)
                    #pragma unroll
                    for (int k2 = 0; k2 < 3; k2++)
                        r27[(k0*3 + k1)*3 + k2] = tile[k0*1156 + (d1 + k1)*34 + (d2 + k2)];
            #pragma unroll
            for (int j = 0; j < 8; j++) {
                const float* wb = w + ((size_t)(co0 + j)*CC + ci)*27;
                float a = acc[q][j];
                #pragma unroll
                for (int k = 0; k < 27; k++) a = fmaf(r27[k], wb[k], a);
                acc[q][j] = a;
            }
        }
    }
    // write outputs (coalesced)
    #pragma unroll
    for (int j = 0; j < 8; j++) {
        size_t obase = ((size_t)(b*CC + co0 + j))*R3 + (size_t)d0 * 1024;
        #pragma unroll
        for (int q = 0; q < 4; q++) out[obase + tid + q*256] = acc[q][j];
    }
    // BN stats: per-channel sum / sumsq
    for (int j = 0; j < 8; j++) {
        float s = 0.f, s2 = 0.f;
        #pragma unroll
        for (int q = 0; q < 4; q++) { s += acc[q][j]; s2 += acc[q][j]*acc[q][j]; }
        __syncthreads();
        tile[tid] = s; tile[256 + tid] = s2;
        __syncthreads();
        for (int off = 128; off > 0; off >>= 1) {
            if (tid < off) { tile[tid] += tile[tid + off]; tile[256 + tid] += tile[256 + tid + off]; }
            __syncthreads();
        }
        if (tid == 0) { atomicAdd(&ssum[co0 + j], tile[0]); atomicAdd(&ssq[co0 + j], tile[256]); }
    }
}

// ---------------- BN finalize / apply ----------------
__global__ void k_finalize(const float* __restrict__ ssum, const float* __restrict__ ssq,
                           const float* __restrict__ gamma, const float* __restrict__ beta,
                           float* __restrict__ scale, float* __restrict__ shift) {
    int c = threadIdx.x;
    const float cntf = 262144.0f;   // B*R3 == B*N
    float m = ssum[c] / cntf;
    float v = ssq[c] / cntf - m*m;
    float sc = gamma[c] * rsqrtf(v + BN_EPS);
    scale[c] = sc;
    shift[c] = beta[c] - m*sc;
}

__global__ void k_bnleaky(float* __restrict__ x, const float* __restrict__ scale,
                          const float* __restrict__ shift) {
    size_t tot = (size_t)BB * CC * R3;
    for (size_t i = (size_t)blockIdx.x*256 + threadIdx.x; i < tot; i += (size_t)gridDim.x*256) {
        int c = (int)((i >> 15) & 63);
        float v = x[i]*scale[c] + shift[c];
        x[i] = v >= 0.f ? v : 0.1f*v;
    }
}

// ---------------- point branch stats ----------------
__global__ void k_point_stats(const float* __restrict__ feat, const float* __restrict__ wp,
                              const float* __restrict__ bp,
                              float* __restrict__ ssum, float* __restrict__ ssq) {
    __shared__ float sb1[256], sb2[256];
    int b = blockIdx.z, co = blockIdx.y;
    int n = blockIdx.x * 256 + threadIdx.x;
    float a = bp[co];
    const float* wr = wp + co*CC;
    #pragma unroll 8
    for (int ci = 0; ci < CC; ci++)
        a = fmaf(wr[ci], feat[((size_t)(b*CC + ci))*NPT + n], a);
    sb1[threadIdx.x] = a; sb2[threadIdx.x] = a*a; __syncthreads();
    for (int off = 128; off > 0; off >>= 1) {
        if (threadIdx.x < off) {
            sb1[threadIdx.x] += sb1[threadIdx.x + off];
            sb2[threadIdx.x] += sb2[threadIdx.x + off];
        }
        __syncthreads();
    }
    if (threadIdx.x == 0) { atomicAdd(&ssum[co], sb1[0]); atomicAdd(&ssq[co], sb2[0]); }
}

// ---------------- devoxelize + point branch + add ----------------
__global__ void k_final(const float* __restrict__ x2, const float* __restrict__ norm,
                        const float* __restrict__ feat, const float* __restrict__ wp,
                        const float* __restrict__ bp,
                        const float* __restrict__ scale, const float* __restrict__ shift,
                        float* __restrict__ out) {
    int b = blockIdx.z, co = blockIdx.y;
    int n = blockIdx.x * 256 + threadIdx.x;
    // point branch (recompute) + BN + ReLU
    float a = bp[co];
    const float* wr = wp + co*CC;
    #pragma unroll 8
    for (int ci = 0; ci < CC; ci++)
        a = fmaf(wr[ci], feat[((size_t)(b*CC + ci))*NPT + n], a);
    a = a*scale[co] + shift[co];
    a = fmaxf(a, 0.f);
    // trilinear devoxelize
    float v0 = norm[((size_t)b*3 + 0)*NPT + n];
    float v1 = norm[((size_t)b*3 + 1)*NPT + n];
    float v2 = norm[((size_t)b*3 + 2)*NPT + n];
    int l0 = (int)floorf(v0), l1 = (int)floorf(v1), l2 = (int)floorf(v2);
    float f0 = v0 - (float)l0, f1 = v1 - (float)l1, f2 = v2 - (float)l2;
    int h0 = min(l0 + 1, RR - 1), h1 = min(l1 + 1, RR - 1), h2 = min(l2 + 1, RR - 1);
    const float* g = x2 + ((size_t)(b*CC + co))*R3;
    float acc = 0.f;
    #pragma unroll
    for (int dx = 0; dx < 2; dx++) {
        int xi = dx ? h0 : l0; float wx = dx ? f0 : 1.f - f0;
        #pragma unroll
        for (int dy = 0; dy < 2; dy++) {
            int yi = dy ? h1 : l1; float wy = dy ? f1 : 1.f - f1;
            #pragma unroll
            for (int dz = 0; dz < 2; dz++) {
                int zi = dz ? h2 : l2; float wz = dz ? f2 : 1.f - f2;
                acc += g[(xi*RR + yi)*RR + zi] * (wx*wy*wz);
            }
        }
    }
    out[((size_t)(b*CC + co))*NPT + n] = acc + a;
}

extern "C" void kernel_launch(void* const* d_in, const int* in_sizes, int n_in,
                              void* d_out, int out_size, void* d_ws, size_t ws_size,
                              hipStream_t stream) {
    const float* feat   = (const float*)d_in[0];
    const float* coords = (const float*)d_in[1];
    const float* w1  = (const float*)d_in[2];
    const float* b1  = (const float*)d_in[3];
    const float* g1  = (const float*)d_in[4];
    const float* be1 = (const float*)d_in[5];
    const float* w2  = (const float*)d_in[6];
    const float* b2  = (const float*)d_in[7];
    const float* g2  = (const float*)d_in[8];
    const float* be2 = (const float*)d_in[9];
    const float* wp  = (const float*)d_in[10];
    const float* bp  = (const float*)d_in[11];
    const float* gp  = (const float*)d_in[12];
    const float* bep = (const float*)d_in[13];
    float* out = (float*)d_out;
    float* ws  = (float*)d_ws;

    // workspace layout (floats)
    float* mean   = ws;                       // 24
    float* maxmag = ws + 24;                  // 8
    float* stats  = ws + 32;                  // 6*64 = 384
    float* sc     = ws + 416;                 // 6*64 = 384
    float* norm   = ws + 1024;                // B*3*N = 786432
    int*   idx    = (int*)(ws + 1024 + 786432);         // B*N = 262144
    float* cnt    = ws + 1024 + 786432 + 262144;        // B*R3 = 262144
    float* gA     = cnt + 262144;                        // B*C*R3 = 16777216
    float* gB     = gA + 16777216;                       // B*C*R3 = 16777216

    hipMemsetAsync(stats, 0, 384 * sizeof(float), stream);
    hipMemsetAsync(cnt,   0, 262144 * sizeof(float), stream);
    hipMemsetAsync(gA,    0, 16777216ull * sizeof(float), stream);

    k_mean  <<<24, 256, 0, stream>>>(coords, mean);
    k_maxmag<<<8, 256, 0, stream>>>(coords, mean, maxmag);
    k_norm  <<<dim3(128, 8), 256, 0, stream>>>(coords, mean, maxmag, norm, idx, cnt);
    k_scatter<<<dim3(128, 64, 8), 256, 0, stream>>>(feat, idx, gA);
    k_divcnt<<<4096, 256, 0, stream>>>(gA, cnt);

    k_conv<<<dim3(32, 8, 8), 256, 0, stream>>>(gA, gB, w1, b1, stats, stats + 64);
    k_finalize<<<1, 64, 0, stream>>>(stats, stats + 64, g1, be1, sc, sc + 64);
    k_bnleaky<<<4096, 256, 0, stream>>>(gB, sc, sc + 64);

    k_conv<<<dim3(32, 8, 8), 256, 0, stream>>>(gB, gA, w2, b2, stats + 128, stats + 192);
    k_finalize<<<1, 64, 0, stream>>>(stats + 128, stats + 192, g2, be2, sc + 128, sc + 192);
    k_bnleaky<<<4096, 256, 0, stream>>>(gA, sc + 128, sc + 192);

    k_point_stats<<<dim3(128, 64, 8), 256, 0, stream>>>(feat, wp, bp, stats + 256, stats + 320);
    k_finalize<<<1, 64, 0, stream>>>(stats + 256, stats + 320, gp, bep, sc + 256, sc + 320);
    k_final<<<dim3(128, 64, 8), 256, 0, stream>>>(gA, norm, feat, wp, bp, sc + 256, sc + 320, out);
}